// Round 2
// baseline (7535.584 us; speedup 1.0000x reference)
//
#include <hip/hip_runtime.h>

#define N_NODES 50000
#define N_EDGES 800000

typedef unsigned short u16;

__device__ __forceinline__ float b2f(u16 u) {
    union { unsigned int i; float f; } v; v.i = ((unsigned int)u) << 16; return v.f;
}
__device__ __forceinline__ u16 f2b(float f) {
    union { float f; unsigned int i; } v; v.f = f;
    unsigned int x = v.i;
    unsigned int r = (x + 0x7fffu + ((x >> 16) & 1u)) >> 16;
    return (u16)r;
}

// dot of a 64-wide LDS fp32 row against LDS bf16 weight matrix [64][64], col = lane
__device__ __forceinline__ float dot64(const float* xrow, const u16* w, int lane, float acc) {
    #pragma unroll
    for (int k = 0; k < 64; k += 4) {
        const float4 xv = *(const float4*)(xrow + k);
        acc = fmaf(xv.x, b2f(w[(k + 0) * 64 + lane]), acc);
        acc = fmaf(xv.y, b2f(w[(k + 1) * 64 + lane]), acc);
        acc = fmaf(xv.z, b2f(w[(k + 2) * 64 + lane]), acc);
        acc = fmaf(xv.w, b2f(w[(k + 3) * 64 + lane]), acc);
    }
    return acc;
}

// ---------------- edge pass: e' = MLP([h[src], h[dst], e]); agg[dst] += e' ----
__global__ __launch_bounds__(256, 2)
void edge_pass(const float* __restrict__ h,
               const float* __restrict__ e_in32,   // fp32 edge input (layer 0) or null
               const u16* __restrict__ e_in16,     // bf16 edge state (layers 1,2)
               u16* __restrict__ e_out,
               const int* __restrict__ src,
               const int* __restrict__ dst,
               const float* __restrict__ W0, const float* __restrict__ W1,
               const float* __restrict__ W2, const float* __restrict__ W3,
               const float* __restrict__ b0, const float* __restrict__ b1,
               const float* __restrict__ b2, const float* __restrict__ b3,
               float* __restrict__ agg)
{
    __shared__ u16 w0[192 * 64];
    __shared__ u16 w1[64 * 64];
    __shared__ u16 w2[64 * 64];
    __shared__ u16 w3[64 * 64];
    __shared__ float bias[4][64];
    __shared__ float xs[4][192];
    __shared__ float hidA[4][64];
    __shared__ float hidB[4][64];

    const int tid = threadIdx.x;
    for (int i = tid; i < 192 * 64; i += 256) w0[i] = f2b(W0[i]);
    for (int i = tid; i < 64 * 64; i += 256) {
        w1[i] = f2b(W1[i]); w2[i] = f2b(W2[i]); w3[i] = f2b(W3[i]);
    }
    {
        const int which = tid >> 6, j = tid & 63;
        const float* bp = (which == 0) ? b0 : (which == 1) ? b1 : (which == 2) ? b2 : b3;
        bias[which][j] = bp[j];
    }
    __syncthreads();

    const int slot = tid >> 6;
    const int lane = tid & 63;
    const int base = blockIdx.x * 64;  // 64 edges per block

    for (int it = 0; it < 64; it += 4) {
        const int eid = base + it + slot;
        const int sv = src[eid];
        const int tv = dst[eid];
        xs[slot][lane]      = h[(size_t)sv * 64 + lane];
        xs[slot][64 + lane] = h[(size_t)tv * 64 + lane];
        xs[slot][128 + lane] = e_in32 ? e_in32[(size_t)eid * 64 + lane]
                                      : b2f(e_in16[(size_t)eid * 64 + lane]);
        __syncthreads();

        // layer 1: 192 -> 64
        float acc = bias[0][lane];
        #pragma unroll
        for (int k = 0; k < 192; k += 4) {
            const float4 xv = *(const float4*)&xs[slot][k];
            acc = fmaf(xv.x, b2f(w0[(k + 0) * 64 + lane]), acc);
            acc = fmaf(xv.y, b2f(w0[(k + 1) * 64 + lane]), acc);
            acc = fmaf(xv.z, b2f(w0[(k + 2) * 64 + lane]), acc);
            acc = fmaf(xv.w, b2f(w0[(k + 3) * 64 + lane]), acc);
        }
        hidA[slot][lane] = fmaxf(acc, 0.f);
        __syncthreads();

        // layer 2
        acc = dot64(hidA[slot], w1, lane, bias[1][lane]);
        hidB[slot][lane] = fmaxf(acc, 0.f);
        __syncthreads();

        // layer 3
        acc = dot64(hidB[slot], w2, lane, bias[2][lane]);
        hidA[slot][lane] = fmaxf(acc, 0.f);
        __syncthreads();

        // layer 4 (output, ReLU like all others)
        acc = dot64(hidA[slot], w3, lane, bias[3][lane]);
        const float out = fmaxf(acc, 0.f);
        e_out[(size_t)eid * 64 + lane] = f2b(out);
        atomicAdd(&agg[(size_t)tv * 64 + lane], out);
        __syncthreads();
    }
}

// ---------------- node pass: h' = MLP([agg, h]) -----------------------------
__global__ __launch_bounds__(256, 2)
void node_pass(const float* __restrict__ agg,
               const float* __restrict__ hin,
               const float* __restrict__ W0, const float* __restrict__ W1,
               const float* __restrict__ W2, const float* __restrict__ W3,
               const float* __restrict__ b0, const float* __restrict__ b1,
               const float* __restrict__ b2, const float* __restrict__ b3,
               float* __restrict__ hout)
{
    __shared__ u16 w0[128 * 64];
    __shared__ u16 w1[64 * 64];
    __shared__ u16 w2[64 * 64];
    __shared__ u16 w3[64 * 64];
    __shared__ float bias[4][64];
    __shared__ float xs[4][128];
    __shared__ float hidA[4][64];
    __shared__ float hidB[4][64];

    const int tid = threadIdx.x;
    for (int i = tid; i < 128 * 64; i += 256) w0[i] = f2b(W0[i]);
    for (int i = tid; i < 64 * 64; i += 256) {
        w1[i] = f2b(W1[i]); w2[i] = f2b(W2[i]); w3[i] = f2b(W3[i]);
    }
    {
        const int which = tid >> 6, j = tid & 63;
        const float* bp = (which == 0) ? b0 : (which == 1) ? b1 : (which == 2) ? b2 : b3;
        bias[which][j] = bp[j];
    }
    __syncthreads();

    const int slot = tid >> 6;
    const int lane = tid & 63;
    const int base = blockIdx.x * 64;  // 64 nodes per block

    for (int it = 0; it < 64; it += 4) {
        const int nid = base + it + slot;
        const bool ok = (nid < N_NODES);
        const int nc = ok ? nid : 0;
        xs[slot][lane]      = agg[(size_t)nc * 64 + lane];
        xs[slot][64 + lane] = hin[(size_t)nc * 64 + lane];
        __syncthreads();

        // layer 1: 128 -> 64
        float acc = bias[0][lane];
        #pragma unroll
        for (int k = 0; k < 128; k += 4) {
            const float4 xv = *(const float4*)&xs[slot][k];
            acc = fmaf(xv.x, b2f(w0[(k + 0) * 64 + lane]), acc);
            acc = fmaf(xv.y, b2f(w0[(k + 1) * 64 + lane]), acc);
            acc = fmaf(xv.z, b2f(w0[(k + 2) * 64 + lane]), acc);
            acc = fmaf(xv.w, b2f(w0[(k + 3) * 64 + lane]), acc);
        }
        hidA[slot][lane] = fmaxf(acc, 0.f);
        __syncthreads();

        acc = dot64(hidA[slot], w1, lane, bias[1][lane]);
        hidB[slot][lane] = fmaxf(acc, 0.f);
        __syncthreads();

        acc = dot64(hidB[slot], w2, lane, bias[2][lane]);
        hidA[slot][lane] = fmaxf(acc, 0.f);
        __syncthreads();

        acc = dot64(hidA[slot], w3, lane, bias[3][lane]);
        if (ok) hout[(size_t)nid * 64 + lane] = fmaxf(acc, 0.f);
        __syncthreads();
    }
}

extern "C" void kernel_launch(void* const* d_in, const int* in_sizes, int n_in,
                              void* d_out, int out_size, void* d_ws, size_t ws_size,
                              hipStream_t stream)
{
    // setup_inputs order: node_h, edge_h, src, dst, then for i in 0..3:
    //   eW{i}, eb{i}, nW{i}, nb{i}   (interleaved!)
    const float* node_h = (const float*)d_in[0];
    const float* edge_h = (const float*)d_in[1];
    const int* src      = (const int*)d_in[2];
    const int* dst      = (const int*)d_in[3];
    const float* eW[4] = {(const float*)d_in[4],  (const float*)d_in[8],
                          (const float*)d_in[12], (const float*)d_in[16]};
    const float* eb[4] = {(const float*)d_in[5],  (const float*)d_in[9],
                          (const float*)d_in[13], (const float*)d_in[17]};
    const float* nW[4] = {(const float*)d_in[6],  (const float*)d_in[10],
                          (const float*)d_in[14], (const float*)d_in[18]};
    const float* nb[4] = {(const float*)d_in[7],  (const float*)d_in[11],
                          (const float*)d_in[15], (const float*)d_in[19]};

    // workspace layout: e state (bf16, 102.4MB) | h state (fp32, 12.8MB) | agg (fp32, 12.8MB)
    u16*   ebuf = (u16*)d_ws;
    float* hbuf = (float*)(ebuf + (size_t)N_EDGES * 64);
    float* agg  = hbuf + (size_t)N_NODES * 64;

    hipMemcpyAsync(hbuf, node_h, (size_t)N_NODES * 64 * sizeof(float),
                   hipMemcpyDeviceToDevice, stream);

    for (int l = 0; l < 3; ++l) {
        hipMemsetAsync(agg, 0, (size_t)N_NODES * 64 * sizeof(float), stream);
        edge_pass<<<N_EDGES / 64, 256, 0, stream>>>(
            hbuf,
            (l == 0) ? edge_h : nullptr, ebuf, ebuf,
            src, dst,
            eW[0] + (size_t)l * 192 * 64, eW[1] + (size_t)l * 64 * 64,
            eW[2] + (size_t)l * 64 * 64,  eW[3] + (size_t)l * 64 * 64,
            eb[0] + l * 64, eb[1] + l * 64, eb[2] + l * 64, eb[3] + l * 64,
            agg);
        float* hout = (l == 2) ? (float*)d_out : hbuf;
        node_pass<<<(N_NODES + 63) / 64, 256, 0, stream>>>(
            agg, hbuf,
            nW[0] + (size_t)l * 128 * 64, nW[1] + (size_t)l * 64 * 64,
            nW[2] + (size_t)l * 64 * 64,  nW[3] + (size_t)l * 64 * 64,
            nb[0] + l * 64, nb[1] + l * 64, nb[2] + l * 64, nb[3] + l * 64,
            hout);
    }
}

// Round 3
// 2283.466 us; speedup vs baseline: 3.3001x; 3.3001x over previous
//
#include <hip/hip_runtime.h>

#define N_NODES 50000
#define N_EDGES 800000

typedef unsigned short u16;
typedef __attribute__((ext_vector_type(8))) short short8;
typedef __attribute__((ext_vector_type(4))) float f32x4;

#define MFMA16(a, b, c) __builtin_amdgcn_mfma_f32_16x16x32_bf16((a), (b), (c), 0, 0, 0)

__device__ __forceinline__ float b2f(u16 u) {
    union { unsigned int i; float f; } v; v.i = ((unsigned int)u) << 16; return v.f;
}
__device__ __forceinline__ u16 f2b(float f) {
    union { float f; unsigned int i; } v; v.f = f;
    unsigned int x = v.i;
    unsigned int r = (x + 0x7fffu + ((x >> 16) & 1u)) >> 16;
    return (u16)r;
}

// ===================== MFMA edge pass ========================================
// Per block: 64 edges, 4 waves, wave w owns edges [w*16, w*16+16).
// GEMM: X[64,192] @ W0[192,64] -> relu -> @W1 -> relu -> @W2 -> relu -> @W3 -> relu
// A-frag (16x16x32): A[m=lane&15][k=(lane>>4)*8+j]
// B-frag:            B[k=(lane>>4)*8+j][n=lane&15]
// C/D:               C[row=(lane>>4)*4+r][col=lane&15]
#define XROW 200        // 192 + 8 pad (u16) -> row stride 400B, banks spread
#define HROW 72         // 64 + 8 pad (u16)
#define HB_OFF 4608     // HB base inside xbuf (u16 units); HA at 0

__global__ __launch_bounds__(256, 2)
void edge_pass(const float* __restrict__ h,
               const float* __restrict__ e_in32,   // fp32 edge input (layer 0) or null
               const u16* __restrict__ e_in16,     // bf16 edge state (layers 1,2)
               u16* __restrict__ e_out,
               const int* __restrict__ src,
               const int* __restrict__ dst,
               const float* __restrict__ W0, const float* __restrict__ W1,
               const float* __restrict__ W2, const float* __restrict__ W3,
               const float* __restrict__ b0, const float* __restrict__ b1,
               const float* __restrict__ b2, const float* __restrict__ b3,
               float* __restrict__ agg)
{
    __shared__ u16 w0s[6 * 4 * 64 * 8];       // [ks][nt][lane][j] 24576B
    __shared__ u16 w123s[3][2 * 4 * 64 * 8];  // 3 x 8192B
    __shared__ float biasS[4 * 64];
    __shared__ u16 xbuf[64 * XROW];           // X tile; reused as HA/HB after preload

    const int tid = threadIdx.x;

    // ---- stage swizzled weights (B-fragment order) ----
    for (int i = tid; i < 6 * 4 * 64; i += 256) {
        const int ks = i >> 8, nt = (i >> 6) & 3, L = i & 63;
        const int n  = nt * 16 + (L & 15);
        const int kb = ks * 32 + (L >> 4) * 8;
        #pragma unroll
        for (int j = 0; j < 8; ++j) w0s[i * 8 + j] = f2b(W0[(kb + j) * 64 + n]);
    }
    for (int l = 0; l < 3; ++l) {
        const float* W = (l == 0) ? W1 : (l == 1) ? W2 : W3;
        for (int i = tid; i < 2 * 4 * 64; i += 256) {
            const int ks = i >> 8, nt = (i >> 6) & 3, L = i & 63;
            const int n  = nt * 16 + (L & 15);
            const int kb = ks * 32 + (L >> 4) * 8;
            #pragma unroll
            for (int j = 0; j < 8; ++j) w123s[l][i * 8 + j] = f2b(W[(kb + j) * 64 + n]);
        }
    }
    {
        const int which = tid >> 6, j = tid & 63;
        const float* bp = (which == 0) ? b0 : (which == 1) ? b1 : (which == 2) ? b2 : b3;
        biasS[which * 64 + j] = bp[j];
    }

    const int w    = tid >> 6;
    const int lane = tid & 63;
    const int col  = lane & 15;
    const int q    = lane >> 4;
    const int base = blockIdx.x * 64;

    // ---- stage X rows for this wave's 16 edges (bf16, padded rows) ----
    #pragma unroll 4
    for (int e = 0; e < 16; ++e) {
        const int row = w * 16 + e;
        const int eid = base + row;
        const int sv = src[eid], tv = dst[eid];
        xbuf[row * XROW + lane]       = f2b(h[(size_t)sv * 64 + lane]);
        xbuf[row * XROW + 64 + lane]  = f2b(h[(size_t)tv * 64 + lane]);
        xbuf[row * XROW + 128 + lane] = e_in32 ? f2b(e_in32[(size_t)eid * 64 + lane])
                                               : e_in16[(size_t)eid * 64 + lane];
    }
    __syncthreads();  // weights staged by all; X rows are wave-local

    // ---- preload layer-1 A-fragments so xbuf can be reused for H ping-pong ----
    short8 af[6];
    #pragma unroll
    for (int ks = 0; ks < 6; ++ks)
        af[ks] = *(const short8*)&xbuf[(w * 16 + col) * XROW + ks * 32 + q * 8];
    __syncthreads();  // all waves preloaded; xbuf region now reusable

    // dst nodes for this lane's 4 C-rows (for the final atomics)
    int tvr[4];
    #pragma unroll
    for (int r = 0; r < 4; ++r) tvr[r] = dst[base + w * 16 + q * 4 + r];

    // ---- layer 1: K=192 -> HA ----
    #pragma unroll
    for (int nt = 0; nt < 4; ++nt) {
        f32x4 acc = {0.f, 0.f, 0.f, 0.f};
        #pragma unroll
        for (int ks = 0; ks < 6; ++ks)
            acc = MFMA16(af[ks], *(const short8*)&w0s[((ks * 4 + nt) * 64 + lane) * 8], acc);
        const float bv = biasS[0 * 64 + nt * 16 + col];
        #pragma unroll
        for (int r = 0; r < 4; ++r) {
            const float v = fmaxf(acc[r] + bv, 0.f);
            xbuf[(w * 16 + q * 4 + r) * HROW + nt * 16 + col] = f2b(v);  // HA
        }
    }

    // ---- layers 2..4: K=64, ping-pong HA<->HB ----
    #pragma unroll
    for (int li = 0; li < 3; ++li) {
        const int src_off = (li & 1) ? HB_OFF : 0;      // L2 reads HA, L3 reads HB, L4 reads HA
        const int dst_off = (li & 1) ? 0 : HB_OFF;
        short8 ah[2];
        #pragma unroll
        for (int ks = 0; ks < 2; ++ks)
            ah[ks] = *(const short8*)&xbuf[src_off + (w * 16 + col) * HROW + ks * 32 + q * 8];
        #pragma unroll
        for (int nt = 0; nt < 4; ++nt) {
            f32x4 acc = {0.f, 0.f, 0.f, 0.f};
            #pragma unroll
            for (int ks = 0; ks < 2; ++ks)
                acc = MFMA16(ah[ks], *(const short8*)&w123s[li][((ks * 4 + nt) * 64 + lane) * 8], acc);
            const float bv = biasS[(li + 1) * 64 + nt * 16 + col];
            #pragma unroll
            for (int r = 0; r < 4; ++r) {
                const float v = fmaxf(acc[r] + bv, 0.f);
                xbuf[dst_off + (w * 16 + q * 4 + r) * HROW + nt * 16 + col] = f2b(v);
                if (li == 2) {  // final layer: fp32 atomic scatter-add into agg
                    atomicAdd(&agg[(size_t)tvr[r] * 64 + nt * 16 + col], v);
                }
            }
        }
    }

    // ---- coalesced e_out store from HB (layer-4 output, bf16) ----
    #pragma unroll 4
    for (int e = 0; e < 16; ++e) {
        const int row = w * 16 + e;
        e_out[(size_t)(base + row) * 64 + lane] = xbuf[HB_OFF + row * HROW + lane];
    }
}

// ===================== node pass (fp32 vector, unchanged) ====================
__global__ __launch_bounds__(256, 2)
void node_pass(const float* __restrict__ agg,
               const float* __restrict__ hin,
               const float* __restrict__ W0, const float* __restrict__ W1,
               const float* __restrict__ W2, const float* __restrict__ W3,
               const float* __restrict__ b0, const float* __restrict__ b1,
               const float* __restrict__ b2, const float* __restrict__ b3,
               float* __restrict__ hout)
{
    __shared__ u16 w0[128 * 64];
    __shared__ u16 w1[64 * 64];
    __shared__ u16 w2[64 * 64];
    __shared__ u16 w3[64 * 64];
    __shared__ float bias[4][64];
    __shared__ float xs[4][128];
    __shared__ float hidA[4][64];
    __shared__ float hidB[4][64];

    const int tid = threadIdx.x;
    for (int i = tid; i < 128 * 64; i += 256) w0[i] = f2b(W0[i]);
    for (int i = tid; i < 64 * 64; i += 256) {
        w1[i] = f2b(W1[i]); w2[i] = f2b(W2[i]); w3[i] = f2b(W3[i]);
    }
    {
        const int which = tid >> 6, j = tid & 63;
        const float* bp = (which == 0) ? b0 : (which == 1) ? b1 : (which == 2) ? b2 : b3;
        bias[which][j] = bp[j];
    }
    __syncthreads();

    const int slot = tid >> 6;
    const int lane = tid & 63;
    const int base = blockIdx.x * 64;

    for (int it = 0; it < 64; it += 4) {
        const int nid = base + it + slot;
        const bool ok = (nid < N_NODES);
        const int nc = ok ? nid : 0;
        xs[slot][lane]      = agg[(size_t)nc * 64 + lane];
        xs[slot][64 + lane] = hin[(size_t)nc * 64 + lane];
        __syncthreads();

        float acc = bias[0][lane];
        #pragma unroll
        for (int k = 0; k < 128; k += 4) {
            const float4 xv = *(const float4*)&xs[slot][k];
            acc = fmaf(xv.x, b2f(w0[(k + 0) * 64 + lane]), acc);
            acc = fmaf(xv.y, b2f(w0[(k + 1) * 64 + lane]), acc);
            acc = fmaf(xv.z, b2f(w0[(k + 2) * 64 + lane]), acc);
            acc = fmaf(xv.w, b2f(w0[(k + 3) * 64 + lane]), acc);
        }
        hidA[slot][lane] = fmaxf(acc, 0.f);
        __syncthreads();

        acc = bias[1][lane];
        #pragma unroll
        for (int k = 0; k < 64; k += 4) {
            const float4 xv = *(const float4*)&hidA[slot][k];
            acc = fmaf(xv.x, b2f(w1[(k + 0) * 64 + lane]), acc);
            acc = fmaf(xv.y, b2f(w1[(k + 1) * 64 + lane]), acc);
            acc = fmaf(xv.z, b2f(w1[(k + 2) * 64 + lane]), acc);
            acc = fmaf(xv.w, b2f(w1[(k + 3) * 64 + lane]), acc);
        }
        hidB[slot][lane] = fmaxf(acc, 0.f);
        __syncthreads();

        acc = bias[2][lane];
        #pragma unroll
        for (int k = 0; k < 64; k += 4) {
            const float4 xv = *(const float4*)&hidB[slot][k];
            acc = fmaf(xv.x, b2f(w2[(k + 0) * 64 + lane]), acc);
            acc = fmaf(xv.y, b2f(w2[(k + 1) * 64 + lane]), acc);
            acc = fmaf(xv.z, b2f(w2[(k + 2) * 64 + lane]), acc);
            acc = fmaf(xv.w, b2f(w2[(k + 3) * 64 + lane]), acc);
        }
        hidA[slot][lane] = fmaxf(acc, 0.f);
        __syncthreads();

        acc = bias[3][lane];
        #pragma unroll
        for (int k = 0; k < 64; k += 4) {
            const float4 xv = *(const float4*)&hidA[slot][k];
            acc = fmaf(xv.x, b2f(w3[(k + 0) * 64 + lane]), acc);
            acc = fmaf(xv.y, b2f(w3[(k + 1) * 64 + lane]), acc);
            acc = fmaf(xv.z, b2f(w3[(k + 2) * 64 + lane]), acc);
            acc = fmaf(xv.w, b2f(w3[(k + 3) * 64 + lane]), acc);
        }
        if (ok) hout[(size_t)nid * 64 + lane] = fmaxf(acc, 0.f);
        __syncthreads();
    }
}

extern "C" void kernel_launch(void* const* d_in, const int* in_sizes, int n_in,
                              void* d_out, int out_size, void* d_ws, size_t ws_size,
                              hipStream_t stream)
{
    const float* node_h = (const float*)d_in[0];
    const float* edge_h = (const float*)d_in[1];
    const int* src      = (const int*)d_in[2];
    const int* dst      = (const int*)d_in[3];
    const float* eW[4] = {(const float*)d_in[4],  (const float*)d_in[8],
                          (const float*)d_in[12], (const float*)d_in[16]};
    const float* eb[4] = {(const float*)d_in[5],  (const float*)d_in[9],
                          (const float*)d_in[13], (const float*)d_in[17]};
    const float* nW[4] = {(const float*)d_in[6],  (const float*)d_in[10],
                          (const float*)d_in[14], (const float*)d_in[18]};
    const float* nb[4] = {(const float*)d_in[7],  (const float*)d_in[11],
                          (const float*)d_in[15], (const float*)d_in[19]};

    // workspace: e state (bf16, 102.4MB) | h state (fp32, 12.8MB) | agg (fp32, 12.8MB)
    u16*   ebuf = (u16*)d_ws;
    float* hbuf = (float*)(ebuf + (size_t)N_EDGES * 64);
    float* agg  = hbuf + (size_t)N_NODES * 64;

    hipMemcpyAsync(hbuf, node_h, (size_t)N_NODES * 64 * sizeof(float),
                   hipMemcpyDeviceToDevice, stream);

    for (int l = 0; l < 3; ++l) {
        hipMemsetAsync(agg, 0, (size_t)N_NODES * 64 * sizeof(float), stream);
        edge_pass<<<N_EDGES / 64, 256, 0, stream>>>(
            hbuf,
            (l == 0) ? edge_h : nullptr, ebuf, ebuf,
            src, dst,
            eW[0] + (size_t)l * 192 * 64, eW[1] + (size_t)l * 64 * 64,
            eW[2] + (size_t)l * 64 * 64,  eW[3] + (size_t)l * 64 * 64,
            eb[0] + l * 64, eb[1] + l * 64, eb[2] + l * 64, eb[3] + l * 64,
            agg);
        float* hout = (l == 2) ? (float*)d_out : hbuf;
        node_pass<<<(N_NODES + 63) / 64, 256, 0, stream>>>(
            agg, hbuf,
            nW[0] + (size_t)l * 128 * 64, nW[1] + (size_t)l * 64 * 64,
            nW[2] + (size_t)l * 64 * 64,  nW[3] + (size_t)l * 64 * 64,
            nb[0] + l * 64, nb[1] + l * 64, nb[2] + l * 64, nb[3] + l * 64,
            hout);
    }
}

// Round 4
// 1090.731 us; speedup vs baseline: 6.9087x; 2.0935x over previous
//
#include <hip/hip_runtime.h>

#define N_NODES 50000
#define N_EDGES 800000
#define HROW 72   // 16B-aligned row stride (144B) for H tiles in LDS

typedef unsigned short u16;
typedef __attribute__((ext_vector_type(8))) short short8;
typedef __attribute__((ext_vector_type(4))) float f32x4;

#define MFMA16(a, b, c) __builtin_amdgcn_mfma_f32_16x16x32_bf16((a), (b), (c), 0, 0, 0)

__device__ __forceinline__ u16 f2b(float f) {
    union { float f; unsigned int i; } v; v.f = f;
    unsigned int x = v.i;
    return (u16)((x + 0x7fffu + ((x >> 16) & 1u)) >> 16);
}
__device__ __forceinline__ short8 cvt8(const float* p) {
    const float4 a = *(const float4*)p;
    const float4 b = *(const float4*)(p + 4);
    short8 r;
    r[0] = (short)f2b(a.x); r[1] = (short)f2b(a.y); r[2] = (short)f2b(a.z); r[3] = (short)f2b(a.w);
    r[4] = (short)f2b(b.x); r[5] = (short)f2b(b.y); r[6] = (short)f2b(b.z); r[7] = (short)f2b(b.w);
    return r;
}

// ---- one-time weight swizzle into B-fragment order (bf16) -------------------
// out[t][nt][lane][j], t = ks for W0 (ks0 of them) then (W1,W2,W3)x(ks=0,1)
// frag value = W[k = ks*32 + (lane>>4)*8 + j][n = nt*16 + (lane&15)]
__global__ void swizzle_layer(const float* __restrict__ W0, const float* __restrict__ W1,
                              const float* __restrict__ W2, const float* __restrict__ W3,
                              int ks0, u16* __restrict__ out)
{
    const int total = (ks0 + 6) * 2048;
    for (int idx = blockIdx.x * 256 + threadIdx.x; idx < total; idx += gridDim.x * 256) {
        const int t = idx >> 11;
        const float* W; int ks;
        if (t < ks0) { W = W0; ks = t; }
        else { const int u = t - ks0; W = (u < 2) ? W1 : (u < 4) ? W2 : W3; ks = u & 1; }
        const int rem = idx & 2047;
        const int nt = rem >> 9, lane = (rem >> 3) & 63, j = rem & 7;
        const int k = ks * 32 + (lane >> 4) * 8 + j;
        const int n = nt * 16 + (lane & 15);
        out[idx] = f2b(W[k * 64 + n]);
    }
}

// ===================== edge pass (persistent, MFMA) ==========================
// 512 thr = 8 waves; wave owns 16 edges/tile; grid-stride over 6250 tiles of 128.
__global__ __launch_bounds__(512, 4)
void edge_pass(const u16* __restrict__ h16, const float* __restrict__ h32,
               const float* __restrict__ e32, const u16* __restrict__ e16,
               u16* __restrict__ e_out,
               const int* __restrict__ src, const int* __restrict__ dst,
               const u16* __restrict__ wz,
               const float* __restrict__ b0, const float* __restrict__ b1,
               const float* __restrict__ b2, const float* __restrict__ b3,
               float* __restrict__ agg)
{
    __shared__ u16 w0s[6 * 2048];      // layer-1 frags  (24 KB)
    __shared__ u16 w1s[3 * 2 * 2048];  // layers 2-4     (24 KB)
    __shared__ float biasS[256];
    __shared__ u16 hb[8 * 16 * HROW];  // per-wave H tiles (18 KB)

    const int tid = threadIdx.x;
    {   // coalesced 16B copy of pre-swizzled weights
        const uint4* s = (const uint4*)wz;
        uint4* dA = (uint4*)w0s; uint4* dB = (uint4*)w1s;
        #pragma unroll
        for (int i = 0; i < 3; ++i) dA[tid + i * 512] = s[tid + i * 512];
        #pragma unroll
        for (int i = 0; i < 3; ++i) dB[tid + i * 512] = s[1536 + tid + i * 512];
        if (tid < 256) {
            const int which = tid >> 6, j = tid & 63;
            const float* bp = (which == 0) ? b0 : (which == 1) ? b1 : (which == 2) ? b2 : b3;
            biasS[tid] = bp[j];
        }
    }
    __syncthreads();  // the only barrier in the kernel

    const int w = tid >> 6, lane = tid & 63, col = lane & 15, q = lane >> 4;
    u16* hw = &hb[w * 16 * HROW];
    const bool fp = (h32 != nullptr);

    for (int tile = blockIdx.x; tile < N_EDGES / 128; tile += gridDim.x) {
        const int base = tile * 128 + w * 16;
        const int em = base + col;
        const int sv = src[em], tv = dst[em];

        // layer-1 A-fragments direct from global
        short8 af[6];
        if (fp) {
            af[0] = cvt8(&h32[(size_t)sv * 64 + q * 8]);
            af[1] = cvt8(&h32[(size_t)sv * 64 + 32 + q * 8]);
            af[2] = cvt8(&h32[(size_t)tv * 64 + q * 8]);
            af[3] = cvt8(&h32[(size_t)tv * 64 + 32 + q * 8]);
            af[4] = cvt8(&e32[(size_t)em * 64 + q * 8]);
            af[5] = cvt8(&e32[(size_t)em * 64 + 32 + q * 8]);
        } else {
            af[0] = *(const short8*)&h16[(size_t)sv * 64 + q * 8];
            af[1] = *(const short8*)&h16[(size_t)sv * 64 + 32 + q * 8];
            af[2] = *(const short8*)&h16[(size_t)tv * 64 + q * 8];
            af[3] = *(const short8*)&h16[(size_t)tv * 64 + 32 + q * 8];
            af[4] = *(const short8*)&e16[(size_t)em * 64 + q * 8];
            af[5] = *(const short8*)&e16[(size_t)em * 64 + 32 + q * 8];
        }
        int tvr[4];
        #pragma unroll
        for (int r = 0; r < 4; ++r) tvr[r] = dst[base + q * 4 + r];

        // ---- layer 1: K=192 ----
        #pragma unroll
        for (int nt = 0; nt < 4; ++nt) {
            f32x4 acc = {0.f, 0.f, 0.f, 0.f};
            #pragma unroll
            for (int ks = 0; ks < 6; ++ks)
                acc = MFMA16(af[ks], *(const short8*)&w0s[(ks * 4 + nt) * 512 + lane * 8], acc);
            const float bv = biasS[nt * 16 + col];
            #pragma unroll
            for (int r = 0; r < 4; ++r)
                hw[(q * 4 + r) * HROW + nt * 16 + col] = f2b(fmaxf(acc[r] + bv, 0.f));
        }

        // ---- layers 2..4: K=64, single wave-private H buffer ----
        #pragma unroll
        for (int li = 0; li < 3; ++li) {
            const short8 ah0 = *(const short8*)&hw[col * HROW + q * 8];
            const short8 ah1 = *(const short8*)&hw[col * HROW + 32 + q * 8];
            const u16* wls = &w1s[li * 4096];
            #pragma unroll
            for (int nt = 0; nt < 4; ++nt) {
                f32x4 acc = {0.f, 0.f, 0.f, 0.f};
                acc = MFMA16(ah0, *(const short8*)&wls[nt * 512 + lane * 8], acc);
                acc = MFMA16(ah1, *(const short8*)&wls[(4 + nt) * 512 + lane * 8], acc);
                const float bv = biasS[(li + 1) * 64 + nt * 16 + col];
                #pragma unroll
                for (int r = 0; r < 4; ++r) {
                    const float v = fmaxf(acc[r] + bv, 0.f);
                    hw[(q * 4 + r) * HROW + nt * 16 + col] = f2b(v);
                    if (li == 2)
                        atomicAdd(&agg[(size_t)tvr[r] * 64 + nt * 16 + col], v);
                }
            }
        }

        // ---- coalesced e_out store (16 rows x 64 cols, bf16) ----
        const int erow = lane >> 2, echk = lane & 3;
        const short8 o0 = *(const short8*)&hw[erow * HROW + echk * 8];
        const short8 o1 = *(const short8*)&hw[erow * HROW + 32 + echk * 8];
        *(short8*)&e_out[(size_t)(base + erow) * 64 + echk * 8] = o0;
        *(short8*)&e_out[(size_t)(base + erow) * 64 + 32 + echk * 8] = o1;
    }
}

// ===================== node pass (MFMA) ======================================
__global__ __launch_bounds__(512, 4)
void node_pass(const float* __restrict__ agg,
               const u16* __restrict__ h16, const float* __restrict__ h32,
               const u16* __restrict__ wz,
               const float* __restrict__ b0, const float* __restrict__ b1,
               const float* __restrict__ b2, const float* __restrict__ b3,
               u16* __restrict__ hout16, float* __restrict__ hout32)
{
    __shared__ u16 w0s[4 * 2048];      // 16 KB
    __shared__ u16 w1s[3 * 2 * 2048];  // 24 KB
    __shared__ float biasS[256];
    __shared__ u16 hb[8 * 16 * HROW];

    const int tid = threadIdx.x;
    {
        const uint4* s = (const uint4*)wz;
        uint4* dA = (uint4*)w0s; uint4* dB = (uint4*)w1s;
        #pragma unroll
        for (int i = 0; i < 2; ++i) dA[tid + i * 512] = s[tid + i * 512];
        #pragma unroll
        for (int i = 0; i < 3; ++i) dB[tid + i * 512] = s[1024 + tid + i * 512];
        if (tid < 256) {
            const int which = tid >> 6, j = tid & 63;
            const float* bp = (which == 0) ? b0 : (which == 1) ? b1 : (which == 2) ? b2 : b3;
            biasS[tid] = bp[j];
        }
    }
    __syncthreads();

    const int w = tid >> 6, lane = tid & 63, col = lane & 15, q = lane >> 4;
    u16* hw = &hb[w * 16 * HROW];
    const bool fp = (h32 != nullptr);
    const int nTiles = (N_NODES + 127) / 128;

    for (int tile = blockIdx.x; tile < nTiles; tile += gridDim.x) {
        const int base = tile * 128 + w * 16;
        const int nm = base + col;
        const int nmc = (nm < N_NODES) ? nm : 0;

        short8 af[4];
        af[0] = cvt8(&agg[(size_t)nmc * 64 + q * 8]);
        af[1] = cvt8(&agg[(size_t)nmc * 64 + 32 + q * 8]);
        if (fp) {
            af[2] = cvt8(&h32[(size_t)nmc * 64 + q * 8]);
            af[3] = cvt8(&h32[(size_t)nmc * 64 + 32 + q * 8]);
        } else {
            af[2] = *(const short8*)&h16[(size_t)nmc * 64 + q * 8];
            af[3] = *(const short8*)&h16[(size_t)nmc * 64 + 32 + q * 8];
        }

        #pragma unroll
        for (int nt = 0; nt < 4; ++nt) {
            f32x4 acc = {0.f, 0.f, 0.f, 0.f};
            #pragma unroll
            for (int ks = 0; ks < 4; ++ks)
                acc = MFMA16(af[ks], *(const short8*)&w0s[(ks * 4 + nt) * 512 + lane * 8], acc);
            const float bv = biasS[nt * 16 + col];
            #pragma unroll
            for (int r = 0; r < 4; ++r)
                hw[(q * 4 + r) * HROW + nt * 16 + col] = f2b(fmaxf(acc[r] + bv, 0.f));
        }

        #pragma unroll
        for (int li = 0; li < 3; ++li) {
            const short8 ah0 = *(const short8*)&hw[col * HROW + q * 8];
            const short8 ah1 = *(const short8*)&hw[col * HROW + 32 + q * 8];
            const u16* wls = &w1s[li * 4096];
            #pragma unroll
            for (int nt = 0; nt < 4; ++nt) {
                f32x4 acc = {0.f, 0.f, 0.f, 0.f};
                acc = MFMA16(ah0, *(const short8*)&wls[nt * 512 + lane * 8], acc);
                acc = MFMA16(ah1, *(const short8*)&wls[(4 + nt) * 512 + lane * 8], acc);
                const float bv = biasS[(li + 1) * 64 + nt * 16 + col];
                #pragma unroll
                for (int r = 0; r < 4; ++r) {
                    const float v = fmaxf(acc[r] + bv, 0.f);
                    if (li == 2 && hout32) {
                        const int row = base + q * 4 + r;
                        if (row < N_NODES) hout32[(size_t)row * 64 + nt * 16 + col] = v;
                    } else {
                        hw[(q * 4 + r) * HROW + nt * 16 + col] = f2b(v);
                    }
                }
            }
        }

        if (!hout32) {  // staged bf16 store of new h
            const int erow = lane >> 2, echk = lane & 3;
            const int row = base + erow;
            if (row < N_NODES) {
                const short8 o0 = *(const short8*)&hw[erow * HROW + echk * 8];
                const short8 o1 = *(const short8*)&hw[erow * HROW + 32 + echk * 8];
                *(short8*)&hout16[(size_t)row * 64 + echk * 8] = o0;
                *(short8*)&hout16[(size_t)row * 64 + 32 + echk * 8] = o1;
            }
        }
    }
}

extern "C" void kernel_launch(void* const* d_in, const int* in_sizes, int n_in,
                              void* d_out, int out_size, void* d_ws, size_t ws_size,
                              hipStream_t stream)
{
    const float* node_h = (const float*)d_in[0];
    const float* edge_h = (const float*)d_in[1];
    const int* src      = (const int*)d_in[2];
    const int* dst      = (const int*)d_in[3];
    const float* eW[4] = {(const float*)d_in[4],  (const float*)d_in[8],
                          (const float*)d_in[12], (const float*)d_in[16]};
    const float* eb[4] = {(const float*)d_in[5],  (const float*)d_in[9],
                          (const float*)d_in[13], (const float*)d_in[17]};
    const float* nW[4] = {(const float*)d_in[6],  (const float*)d_in[10],
                          (const float*)d_in[14], (const float*)d_in[18]};
    const float* nb[4] = {(const float*)d_in[7],  (const float*)d_in[11],
                          (const float*)d_in[15], (const float*)d_in[19]};

    // ws: ebuf bf16 102.4MB | hbuf bf16 6.4MB | agg fp32 12.8MB | eswz 147KB | nswz 123KB
    u16*   ebuf = (u16*)d_ws;
    u16*   hbuf = ebuf + (size_t)N_EDGES * 64;
    float* agg  = (float*)(hbuf + (size_t)N_NODES * 64);
    u16*   eswz = (u16*)(agg + (size_t)N_NODES * 64);
    u16*   nswz = eswz + 3 * 24576;

    for (int l = 0; l < 3; ++l) {
        swizzle_layer<<<96, 256, 0, stream>>>(
            eW[0] + (size_t)l * 192 * 64, eW[1] + (size_t)l * 4096,
            eW[2] + (size_t)l * 4096, eW[3] + (size_t)l * 4096, 6, eswz + (size_t)l * 24576);
        swizzle_layer<<<80, 256, 0, stream>>>(
            nW[0] + (size_t)l * 128 * 64, nW[1] + (size_t)l * 4096,
            nW[2] + (size_t)l * 4096, nW[3] + (size_t)l * 4096, 4, nswz + (size_t)l * 20480);
    }

    for (int l = 0; l < 3; ++l) {
        hipMemsetAsync(agg, 0, (size_t)N_NODES * 64 * sizeof(float), stream);
        edge_pass<<<1024, 512, 0, stream>>>(
            hbuf, (l == 0) ? node_h : nullptr,
            (l == 0) ? edge_h : nullptr, ebuf, ebuf,
            src, dst, eswz + (size_t)l * 24576,
            eb[0] + l * 64, eb[1] + l * 64, eb[2] + l * 64, eb[3] + l * 64,
            agg);
        node_pass<<<391, 512, 0, stream>>>(
            agg, hbuf, (l == 0) ? node_h : nullptr,
            nswz + (size_t)l * 20480,
            nb[0] + l * 64, nb[1] + l * 64, nb[2] + l * 64, nb[3] + l * 64,
            (l < 2) ? hbuf : nullptr, (l == 2) ? (float*)d_out : nullptr);
    }
}